// Round 6
// baseline (185.471 us; speedup 1.0000x reference)
//
#include <hip/hip_runtime.h>
#include <hip/hip_bf16.h>

// ---------------------------------------------------------------------------
// NaiveFourierKANLayer as GEMM:  y = [cos|sin features][4096 x 32768] * W + b
// R6: 128x256 output tile (single column block) -> A-synthesis amortized over
// 2x MFMAs; grid 256 = 1 block/CU; B double-buffered 2x64KB via
// global_load_lds; s-loop software-pipelined; A synthesized in registers
// (identical math to R5, verified). Convert+init merged into one kernel.
// ---------------------------------------------------------------------------

typedef __attribute__((ext_vector_type(8))) short short8;
typedef __attribute__((ext_vector_type(4))) float f32x4;

#define SPLITK 8
#define ICHUNK (256 / SPLITK)   // 32 i's per block

#define INV2PI 0.15915494309189535f

// ---- bf16x2 pack ----
#if __has_builtin(__builtin_amdgcn_cvt_pk_bf16_f32)
typedef __attribute__((ext_vector_type(2))) __bf16 bf16x2_t;
__device__ __forceinline__ unsigned pkbf16(float a, float b) {
    bf16x2_t v = __builtin_amdgcn_cvt_pk_bf16_f32(a, b);
    return __builtin_bit_cast(unsigned, v);
}
#else
__device__ __forceinline__ unsigned pkbf16(float a, float b) {
    unsigned ua = __builtin_bit_cast(unsigned, a) + 0x8000u;
    unsigned ub = __builtin_bit_cast(unsigned, b) + 0x8000u;
    return __builtin_amdgcn_perm(ub, ua, 0x07060302u);  // [b.hi16 | a.hi16]
}
#endif

__device__ __forceinline__ void dbl2(float c, float s, float& co, float& so) {
    float t = c + c;
    co = __builtin_fmaf(t, c, -1.f);
    so = t * s;
}
__device__ __forceinline__ void rot2(float c, float s, float cr, float sr,
                                     float& co, float& so) {
    float t = s * sr;
    co = __builtin_fmaf(c, cr, -t);
    float u = s * cr;
    so = __builtin_fmaf(c, sr, u);
}

// 8 consecutive harmonics from seeds f_{-1}, f_0 with multiplier m1=2cos(x)
__device__ __forceinline__ short8 chain8(float m1, float fm1, float f0) {
    unsigned r[4];
    float vp = fm1, v = f0;
    #pragma unroll
    for (int h = 0; h < 4; ++h) {
        float v1 = __builtin_fmaf(m1, v, -vp);
        r[h] = pkbf16(v, v1);
        float v2 = __builtin_fmaf(m1, v1, -v);
        vp = v1; v = v2;
    }
    uint4 u; u.x = r[0]; u.y = r[1]; u.z = r[2]; u.w = r[3];
    return __builtin_bit_cast(short8, u);
}

// async 16B global->LDS
__device__ __forceinline__ void async_load16(const void* g, void* l) {
    __builtin_amdgcn_global_load_lds(
        (const __attribute__((address_space(1))) unsigned int*)g,
        (__attribute__((address_space(3))) unsigned int*)l,
        16, 0, 0);
}

// ---------------------------------------------------------------------------
// prep kernel: blocks [0,2048) convert fc -> ws2 image order; [2048,3072) init out.
// Image (per i, 4096 granules of 16B): gi = (s*16 + og)*64 + j*16 + (o&15)
//   og = o>>4, k = s*32 + j*8 (j=0..3), tt = k>>6, g = k&63
//   granule content = bf16(fc[tt][o][i][g..g+7])
// Convert block bid = (i*4 + s)*2 + h: thread o reads 64B (j=2h,2h+1), writes 2 granules.
// ---------------------------------------------------------------------------
__global__ __launch_bounds__(256) void prep_kernel(
    const float* __restrict__ fc, const float* __restrict__ bias,
    unsigned short* __restrict__ ws2, float* __restrict__ out)
{
    const int bid = blockIdx.x;
    const int t = threadIdx.x;
    if (bid < 2048) {
        const int i = bid >> 3, s = (bid >> 1) & 3, h = bid & 1;
        const int o = t;
        const int ka = s * 32 + h * 16;         // k of first granule
        const int tt = ka >> 6, g0 = ka & 63;
        const float4* src = (const float4*)(fc +
            ((((size_t)tt * 256 + o) * 256 + i) * 64 + g0));
        float4 a = src[0], b = src[1], c = src[2], d = src[3];
        uint4 vA, vB;
        vA.x = pkbf16(a.x, a.y); vA.y = pkbf16(a.z, a.w);
        vA.z = pkbf16(b.x, b.y); vA.w = pkbf16(b.z, b.w);
        vB.x = pkbf16(c.x, c.y); vB.y = pkbf16(c.z, c.w);
        vB.z = pkbf16(d.x, d.y); vB.w = pkbf16(d.z, d.w);
        uint4* dst = (uint4*)ws2 + ((size_t)i * 4096 +
                     (size_t)(s * 16 + (o >> 4)) * 64 + h * 32 + (o & 15));
        dst[0]  = vA;    // granule j=2h
        dst[16] = vB;    // granule j=2h+1
    } else {
        int tid = (bid - 2048) * 256 + t;       // 0..262143
        float4 b4 = ((const float4*)bias)[tid & 63];
        ((float4*)out)[tid] = b4;
    }
}

template <bool USE_WS>
__global__ __launch_bounds__(256, 1) void fkan_gemm(
    const float* __restrict__ x, const float* __restrict__ fc,
    const unsigned short* __restrict__ bws, float* __restrict__ out)
{
    __shared__ uint4 Bimg[2][4096];        // 128 KB: coeff image, double-buffered
    __shared__ float xs[ICHUNK][128];      // 16 KB: x[row][i] transposed

    const int t  = threadIdx.x;
    const int l  = t & 63;
    const int w  = t >> 6;
    const int wr = w >> 1, wc = w & 1;     // wave: 64 rows (wr) x 128 cols (wc)
    const int q  = l >> 4;                 // MFMA quad -> k offset 8q
    const int m  = l & 15;                 // MFMA row/col within 16
    const int rowBase = blockIdx.x * 128;
    const int iBase   = blockIdx.z * ICHUNK;

    f32x4 acc[4][8];
    #pragma unroll
    for (int a = 0; a < 4; ++a)
        #pragma unroll
        for (int b = 0; b < 8; ++b) acc[a][b] = (f32x4)0.0f;

    auto stageB = [&](int p, int i) {
        if (USE_WS) {
            const uint4* base = (const uint4*)bws + (size_t)i * 4096;
            #pragma unroll
            for (int cc = 0; cc < 16; ++cc) {
                int c = cc * 4 + w;            // wave-uniform chunk id
                async_load16(base + (size_t)c * 64 + l, (void*)(&Bimg[p][c * 64]));
            }
        } else {
            #pragma unroll
            for (int gg = 0; gg < 16; ++gg) {
                int gi  = gg * 256 + t;
                int sog = gi >> 6, ll = gi & 63;
                int s = sog >> 4, og = sog & 15;
                int o = og * 16 + (ll & 15);
                int k = s * 32 + (ll >> 4) * 8;
                int tt = k >> 6, g = k & 63;
                const float4* p4 = (const float4*)(fc +
                    ((((size_t)tt * 256 + o) * 256 + i) * 64 + g));
                float4 a = p4[0], b = p4[1];
                uint4 v;
                v.x = pkbf16(a.x, a.y); v.y = pkbf16(a.z, a.w);
                v.z = pkbf16(b.x, b.y); v.w = pkbf16(b.z, b.w);
                Bimg[p][gi] = v;
            }
        }
    };

    // ---- preamble: stage B(iter0) + x tile, one barrier ----
    stageB(0, iBase);
    {
        int r = t >> 1, c0 = (t & 1) * 16;
        const float4* px = (const float4*)(x + (size_t)(rowBase + r) * 256 + iBase + c0);
        float4 v0 = px[0], v1 = px[1], v2 = px[2], v3 = px[3];
        float tmp[16] = { v0.x, v0.y, v0.z, v0.w, v1.x, v1.y, v1.z, v1.w,
                          v2.x, v2.y, v2.z, v2.w, v3.x, v3.y, v3.z, v3.w };
        #pragma unroll
        for (int j = 0; j < 16; ++j) xs[c0 + j][r] = tmp[j];
    }
    __syncthreads();

    #pragma unroll 1
    for (int ii = 0; ii < ICHUNK; ++ii) {
        const int p = ii & 1;

        // 1. async-stage next B into the other buffer (flies during 2-4)
        if (ii + 1 < ICHUNK) stageB(p ^ 1, iBase + ii + 1);

        // 2. synthesize A fragments in registers (identical math to R5)
        short8 aF[4][4];   // [rf][s]
        #pragma unroll
        for (int rf = 0; rf < 4; ++rf) {
            float xv = xs[ii][wr * 64 + rf * 16 + m];
            float rev = xv * INV2PI;
            float s1 = __builtin_amdgcn_sinf(rev);
            float c1 = __builtin_amdgcn_cosf(rev);
            const float m1 = c1 + c1;
            float c2, s2, c4, s4, c8, s8, c16, s16, c32, s32;
            dbl2(c1, s1, c2, s2);
            dbl2(c2, s2, c4, s4);
            dbl2(c4, s4, c8, s8);
            dbl2(c8, s8, c16, s16);
            dbl2(c16, s16, c32, s32);
            float c24, s24;
            rot2(c16, s16, c8, s8, c24, s24);
            float cq = (q == 0) ? 1.f : (q == 1) ? c8 : (q == 2) ? c16 : c24;
            float sq = (q == 0) ? 0.f : (q == 1) ? s8 : (q == 2) ? s16 : s24;
            float cq1, sq1, cB, sB, cB1, sB1;
            rot2(cq, sq, c1, s1, cq1, sq1);     // 8q+1
            rot2(cq, sq, c32, s32, cB, sB);     // 8q+32
            rot2(cB, sB, c1, s1, cB1, sB1);     // 8q+33
            aF[rf][0] = chain8(m1, cq, cq1);    // cos, freq 8q+1..8q+8
            aF[rf][1] = chain8(m1, cB, cB1);    // cos, freq 8q+33..
            aF[rf][2] = chain8(m1, sq, sq1);    // sin, freq 8q+1..
            aF[rf][3] = chain8(m1, sB, sB1);    // sin, freq 8q+33..
        }

        // 3. MFMA, s-loop software-pipelined on B fragments
        short8 bFc[8], bFn[8];
        #pragma unroll
        for (int cf = 0; cf < 8; ++cf)
            bFc[cf] = __builtin_bit_cast(short8, Bimg[p][(wc * 8 + cf) * 64 + l]);
        #pragma unroll
        for (int s = 0; s < 4; ++s) {
            if (s < 3) {
                #pragma unroll
                for (int cf = 0; cf < 8; ++cf)
                    bFn[cf] = __builtin_bit_cast(short8,
                        Bimg[p][((s + 1) * 16 + wc * 8 + cf) * 64 + l]);
            }
            #pragma unroll
            for (int rf = 0; rf < 4; ++rf)
                #pragma unroll
                for (int cf = 0; cf < 8; ++cf)
                    acc[rf][cf] = __builtin_amdgcn_mfma_f32_16x16x32_bf16(
                        aF[rf][s], bFc[cf], acc[rf][cf], 0, 0, 0);
            #pragma unroll
            for (int cf = 0; cf < 8; ++cf) bFc[cf] = bFn[cf];
        }

        // 4. one barrier: vmcnt drain covered by steps 2-3
        __syncthreads();
    }

    // epilogue: C/D layout col=l&15, row=(l>>4)*4+e ; splitK via atomics
    const int r0 = rowBase + wr * 64 + (l >> 4) * 4;
    const int c0 = wc * 128 + m;
    #pragma unroll
    for (int rf = 0; rf < 4; ++rf)
        #pragma unroll
        for (int cf = 0; cf < 8; ++cf)
            #pragma unroll
            for (int e = 0; e < 4; ++e)
                atomicAdd(out + (size_t)(r0 + rf * 16 + e) * 256 + (c0 + cf * 16),
                          acc[rf][cf][e]);
}

extern "C" void kernel_launch(void* const* d_in, const int* in_sizes, int n_in,
                              void* d_out, int out_size, void* d_ws, size_t ws_size,
                              hipStream_t stream) {
    const float* x    = (const float*)d_in[0];
    const float* fc   = (const float*)d_in[1];
    const float* bias = (const float*)d_in[2];
    float* out = (float*)d_out;
    unsigned short* bws = (unsigned short*)d_ws;

    const size_t wsNeed = (size_t)256 * 4096 * 16;   // 16.78 MB image-order coeffs
    if (ws_size >= wsNeed) {
        hipLaunchKernelGGL(prep_kernel, dim3(3072), dim3(256), 0, stream,
                           fc, bias, bws, out);
        hipLaunchKernelGGL((fkan_gemm<true>), dim3(32, 1, SPLITK), dim3(256), 0, stream,
                           x, fc, bws, out);
    } else {
        hipLaunchKernelGGL(prep_kernel, dim3(3072), dim3(256), 0, stream,
                           fc, bias, bws, out);   // convert writes clipped ws; unused
        hipLaunchKernelGGL((fkan_gemm<false>), dim3(32, 1, SPLITK), dim3(256), 0, stream,
                           x, fc, bws, out);
    }
}

// Round 7
// 177.073 us; speedup vs baseline: 1.0474x; 1.0474x over previous
//
#include <hip/hip_runtime.h>
#include <hip/hip_bf16.h>

// ---------------------------------------------------------------------------
// NaiveFourierKANLayer as GEMM:  y = [cos|sin features][4096 x 32768] * W + b
// R7: R5 compute config (128x128 tile, B dbuf 2x32KB via global_load_lds, one
// barrier/iter, A synthesized in registers) + XCD-aware 1D grid decode:
// splitK index in the low 3 bits of blockIdx -> all blocks sharing an
// i-window co-reside on one XCD and hit L2 (B traffic 512MB -> ~17MB HBM).
// ---------------------------------------------------------------------------

typedef __attribute__((ext_vector_type(8))) short short8;
typedef __attribute__((ext_vector_type(4))) float f32x4;

#define SPLITK 8
#define ICHUNK (256 / SPLITK)   // 32 i's per block

#define INV2PI 0.15915494309189535f

// ---- bf16x2 pack ----
#if __has_builtin(__builtin_amdgcn_cvt_pk_bf16_f32)
typedef __attribute__((ext_vector_type(2))) __bf16 bf16x2_t;
__device__ __forceinline__ unsigned pkbf16(float a, float b) {
    bf16x2_t v = __builtin_amdgcn_cvt_pk_bf16_f32(a, b);
    return __builtin_bit_cast(unsigned, v);
}
#else
__device__ __forceinline__ unsigned pkbf16(float a, float b) {
    unsigned ua = __builtin_bit_cast(unsigned, a) + 0x8000u;
    unsigned ub = __builtin_bit_cast(unsigned, b) + 0x8000u;
    return __builtin_amdgcn_perm(ub, ua, 0x07060302u);  // [b.hi16 | a.hi16]
}
#endif

__device__ __forceinline__ void dbl2(float c, float s, float& co, float& so) {
    float t = c + c;
    co = __builtin_fmaf(t, c, -1.f);
    so = t * s;
}
__device__ __forceinline__ void rot2(float c, float s, float cr, float sr,
                                     float& co, float& so) {
    float t = s * sr;
    co = __builtin_fmaf(c, cr, -t);
    float u = s * cr;
    so = __builtin_fmaf(c, sr, u);
}

// 8 consecutive harmonics from seeds f_{-1}, f_0 with multiplier m1=2cos(x)
__device__ __forceinline__ short8 chain8(float m1, float fm1, float f0) {
    unsigned r[4];
    float vp = fm1, v = f0;
    #pragma unroll
    for (int h = 0; h < 4; ++h) {
        float v1 = __builtin_fmaf(m1, v, -vp);
        r[h] = pkbf16(v, v1);
        float v2 = __builtin_fmaf(m1, v1, -v);
        vp = v1; v = v2;
    }
    uint4 u; u.x = r[0]; u.y = r[1]; u.z = r[2]; u.w = r[3];
    return __builtin_bit_cast(short8, u);
}

// async 16B global->LDS
__device__ __forceinline__ void async_load16(const void* g, void* l) {
    __builtin_amdgcn_global_load_lds(
        (const __attribute__((address_space(1))) unsigned int*)g,
        (__attribute__((address_space(3))) unsigned int*)l,
        16, 0, 0);
}

// ---------------------------------------------------------------------------
// prep kernel: blocks [0,4096) convert fc -> ws2 (R5 image order, one 16B
// granule per thread); blocks [4096,5120) init out[b][o] = bias[o].
//   flat = bx*2048 + gi ; bx = i*2+y ; gi = (s*8+og)*64 + ll
//   op = og*16 + (ll&15); k = s*32 + (ll>>4)*8; tt = k>>6; g0 = k&63
//   ws2 granule <- bf16(fc[tt][y*128+op][i][g0..g0+7])
// ---------------------------------------------------------------------------
__global__ __launch_bounds__(256) void prep_kernel(
    const float* __restrict__ fc, const float* __restrict__ bias,
    unsigned short* __restrict__ ws2, float* __restrict__ out)
{
    const unsigned bid = blockIdx.x;
    const unsigned t = threadIdx.x;
    if (bid < 4096) {
        unsigned flat = bid * 256 + t;                // 0 .. 2^20-1
        unsigned bx = flat >> 11, gi = flat & 2047;
        unsigned i = bx >> 1, y = bx & 1;
        unsigned sog = gi >> 6, ll = gi & 63;
        unsigned s = sog >> 3, og = sog & 7;
        unsigned op = og * 16 + (ll & 15);
        unsigned k = s * 32 + ((ll >> 4) * 8);
        unsigned tt = k >> 6, g0 = k & 63;
        const float4* src = (const float4*)(fc +
            ((((size_t)tt * 256 + y * 128 + op) * 256 + i) * 64 + g0));
        float4 a = src[0], b = src[1];
        uint4 v;
        v.x = pkbf16(a.x, a.y); v.y = pkbf16(a.z, a.w);
        v.z = pkbf16(b.x, b.y); v.w = pkbf16(b.z, b.w);
        ((uint4*)ws2)[flat] = v;
    } else {
        int tid = (bid - 4096) * 256 + t;             // 0..262143
        float4 b4 = ((const float4*)bias)[tid & 63];
        ((float4*)out)[tid] = b4;
    }
}

template <bool USE_WS>
__global__ __launch_bounds__(256, 2) void fkan_gemm(
    const float* __restrict__ x, const float* __restrict__ fc,
    const unsigned short* __restrict__ bws, float* __restrict__ out)
{
    __shared__ uint4 Bimg[2][2048];        // 64 KB: coeff image, double-buffered
    __shared__ float xs[ICHUNK][128];      // 16 KB: x[row][i] transposed

    const int t  = threadIdx.x;
    const int l  = t & 63;
    const int w  = t >> 6;
    const int wr = w >> 1, wc = w & 1;     // 2x2 waves of 64x64
    const int q  = l >> 4;                 // MFMA quad -> k offset 8q
    const int m  = l & 15;                 // MFMA row within 16

    // XCD-aware decode: z (splitK) in low 3 bits -> XCD = bid % 8 = z.
    // All 64 blocks with equal z share one XCD and stream the same B bytes.
    const int bid = blockIdx.x;
    const int z   = bid & 7;
    const int by  = (bid >> 3) & 1;
    const int bx  = bid >> 4;
    const int rowBase = bx * 128;
    const int iBase   = z * ICHUNK;

    f32x4 acc[4][4];
    #pragma unroll
    for (int a = 0; a < 4; ++a)
        #pragma unroll
        for (int b = 0; b < 4; ++b) acc[a][b] = (f32x4)0.0f;

    auto stageB = [&](int p, int i) {
        if (USE_WS) {
            const unsigned short* base = bws + ((size_t)(i * 2 + by) * 2048) * 8;
            #pragma unroll
            for (int cc = 0; cc < 8; ++cc) {
                int c = cc * 4 + w;
                async_load16(base + (size_t)(c * 64 + l) * 8, (void*)(&Bimg[p][c * 64]));
            }
        } else {
            #pragma unroll
            for (int gg = 0; gg < 8; ++gg) {
                int gi  = gg * 256 + t;
                int sog = gi >> 6, ll = gi & 63;
                int s = sog >> 3, ogb = sog & 7;
                int o = ogb * 16 + (ll & 15);
                int k = s * 32 + (ll >> 4) * 8;
                int tt = k >> 6, g = k & 63;
                const float4* p4 = (const float4*)(fc +
                    ((((size_t)tt * 256 + by * 128 + o) * 256 + i) * 64 + g));
                float4 a = p4[0], b = p4[1];
                uint4 v;
                v.x = pkbf16(a.x, a.y); v.y = pkbf16(a.z, a.w);
                v.z = pkbf16(b.x, b.y); v.w = pkbf16(b.z, b.w);
                Bimg[p][gi] = v;
            }
        }
    };

    // ---- preamble: stage B(iter0) + x tile, one barrier ----
    stageB(0, iBase);
    {
        int r = t >> 1, c0 = (t & 1) * 16;
        const float4* px = (const float4*)(x + (size_t)(rowBase + r) * 256 + iBase + c0);
        float4 v0 = px[0], v1 = px[1], v2 = px[2], v3 = px[3];
        float tmp[16] = { v0.x, v0.y, v0.z, v0.w, v1.x, v1.y, v1.z, v1.w,
                          v2.x, v2.y, v2.z, v2.w, v3.x, v3.y, v3.z, v3.w };
        #pragma unroll
        for (int j = 0; j < 16; ++j) xs[c0 + j][r] = tmp[j];
    }
    __syncthreads();

    #pragma unroll 1
    for (int ii = 0; ii < ICHUNK; ++ii) {
        const int p = ii & 1;

        // 1. async-stage next B into the other buffer (in flight during 2-4)
        if (ii + 1 < ICHUNK) stageB(p ^ 1, iBase + ii + 1);

        // 2. B fragments of current buffer -> regs (16 ds_read_b128)
        short8 bF[4][4];
        #pragma unroll
        for (int s = 0; s < 4; ++s)
            #pragma unroll
            for (int cf = 0; cf < 4; ++cf)
                bF[s][cf] = __builtin_bit_cast(short8,
                    Bimg[p][(s * 8 + wc * 4 + cf) * 64 + l]);

        // 3. synthesize A fragments in registers (HW v_sin/v_cos seeds)
        short8 aF[4][4];   // [rf][s]
        #pragma unroll
        for (int rf = 0; rf < 4; ++rf) {
            float xv = xs[ii][wr * 64 + rf * 16 + m];
            float rev = xv * INV2PI;
            float s1 = __builtin_amdgcn_sinf(rev);
            float c1 = __builtin_amdgcn_cosf(rev);
            const float m1 = c1 + c1;
            float c2, s2, c4, s4, c8, s8, c16, s16, c32, s32;
            dbl2(c1, s1, c2, s2);
            dbl2(c2, s2, c4, s4);
            dbl2(c4, s4, c8, s8);
            dbl2(c8, s8, c16, s16);
            dbl2(c16, s16, c32, s32);
            float c24, s24;
            rot2(c16, s16, c8, s8, c24, s24);
            float cq = (q == 0) ? 1.f : (q == 1) ? c8 : (q == 2) ? c16 : c24;
            float sq = (q == 0) ? 0.f : (q == 1) ? s8 : (q == 2) ? s16 : s24;
            float cq1, sq1, cB, sB, cB1, sB1;
            rot2(cq, sq, c1, s1, cq1, sq1);     // 8q+1
            rot2(cq, sq, c32, s32, cB, sB);     // 8q+32
            rot2(cB, sB, c1, s1, cB1, sB1);     // 8q+33
            aF[rf][0] = chain8(m1, cq, cq1);    // cos, freq 8q+1..8q+8
            aF[rf][1] = chain8(m1, cB, cB1);    // cos, freq 8q+33..
            aF[rf][2] = chain8(m1, sq, sq1);    // sin, freq 8q+1..
            aF[rf][3] = chain8(m1, sB, sB1);    // sin, freq 8q+33..
        }

        // 4. MFMA
        #pragma unroll
        for (int s = 0; s < 4; ++s)
            #pragma unroll
            for (int rf = 0; rf < 4; ++rf)
                #pragma unroll
                for (int cf = 0; cf < 4; ++cf)
                    acc[rf][cf] = __builtin_amdgcn_mfma_f32_16x16x32_bf16(
                        aF[rf][s], bF[s][cf], acc[rf][cf], 0, 0, 0);

        // 5. one barrier: vmcnt drain covered by steps 2-4
        __syncthreads();
    }

    // epilogue: C/D layout col=l&15, row=(l>>4)*4+e ; splitK via atomics
    const int r0 = rowBase + wr * 64 + (l >> 4) * 4;
    const int c0 = by * 128 + wc * 64 + m;
    #pragma unroll
    for (int rf = 0; rf < 4; ++rf)
        #pragma unroll
        for (int cf = 0; cf < 4; ++cf)
            #pragma unroll
            for (int e = 0; e < 4; ++e)
                atomicAdd(out + (size_t)(r0 + rf * 16 + e) * 256 + (c0 + cf * 16),
                          acc[rf][cf][e]);
}

extern "C" void kernel_launch(void* const* d_in, const int* in_sizes, int n_in,
                              void* d_out, int out_size, void* d_ws, size_t ws_size,
                              hipStream_t stream) {
    const float* x    = (const float*)d_in[0];
    const float* fc   = (const float*)d_in[1];
    const float* bias = (const float*)d_in[2];
    float* out = (float*)d_out;
    unsigned short* bws = (unsigned short*)d_ws;

    const size_t wsNeed = (size_t)512 * 2048 * 16;   // 16.78 MB image-order coeffs
    hipLaunchKernelGGL(prep_kernel, dim3(5120), dim3(256), 0, stream,
                       fc, bias, bws, out);
    if (ws_size >= wsNeed) {
        hipLaunchKernelGGL((fkan_gemm<true>), dim3(512), dim3(256), 0, stream,
                           x, fc, bws, out);
    } else {
        hipLaunchKernelGGL((fkan_gemm<false>), dim3(512), dim3(256), 0, stream,
                           x, fc, bws, out);
    }
}

// Round 8
// 173.601 us; speedup vs baseline: 1.0684x; 1.0200x over previous
//
#include <hip/hip_runtime.h>
#include <hip/hip_bf16.h>

// ---------------------------------------------------------------------------
// NaiveFourierKANLayer as GEMM:  y = [cos|sin features][4096 x 32768] * W + b
// R8: R7 loop (verified) + ATOMIC-FREE splitK: each z-block stores its fp32
// partial tile to ws; reduce_kernel sums 8 partials + bias -> out.
// Theory: R3-R7 all pinned at ~108us regardless of loop changes because the
// 8.4M cross-XCD device-scope atomicAdds serialize at the coherence point.
// ---------------------------------------------------------------------------

typedef __attribute__((ext_vector_type(8))) short short8;
typedef __attribute__((ext_vector_type(4))) float f32x4;

#define SPLITK 8
#define ICHUNK (256 / SPLITK)   // 32 i's per block

#define INV2PI 0.15915494309189535f

// ---- bf16x2 pack ----
#if __has_builtin(__builtin_amdgcn_cvt_pk_bf16_f32)
typedef __attribute__((ext_vector_type(2))) __bf16 bf16x2_t;
__device__ __forceinline__ unsigned pkbf16(float a, float b) {
    bf16x2_t v = __builtin_amdgcn_cvt_pk_bf16_f32(a, b);
    return __builtin_bit_cast(unsigned, v);
}
#else
__device__ __forceinline__ unsigned pkbf16(float a, float b) {
    unsigned ua = __builtin_bit_cast(unsigned, a) + 0x8000u;
    unsigned ub = __builtin_bit_cast(unsigned, b) + 0x8000u;
    return __builtin_amdgcn_perm(ub, ua, 0x07060302u);  // [b.hi16 | a.hi16]
}
#endif

__device__ __forceinline__ void dbl2(float c, float s, float& co, float& so) {
    float t = c + c;
    co = __builtin_fmaf(t, c, -1.f);
    so = t * s;
}
__device__ __forceinline__ void rot2(float c, float s, float cr, float sr,
                                     float& co, float& so) {
    float t = s * sr;
    co = __builtin_fmaf(c, cr, -t);
    float u = s * cr;
    so = __builtin_fmaf(c, sr, u);
}

// 8 consecutive harmonics from seeds f_{-1}, f_0 with multiplier m1=2cos(x)
__device__ __forceinline__ short8 chain8(float m1, float fm1, float f0) {
    unsigned r[4];
    float vp = fm1, v = f0;
    #pragma unroll
    for (int h = 0; h < 4; ++h) {
        float v1 = __builtin_fmaf(m1, v, -vp);
        r[h] = pkbf16(v, v1);
        float v2 = __builtin_fmaf(m1, v1, -v);
        vp = v1; v = v2;
    }
    uint4 u; u.x = r[0]; u.y = r[1]; u.z = r[2]; u.w = r[3];
    return __builtin_bit_cast(short8, u);
}

// async 16B global->LDS
__device__ __forceinline__ void async_load16(const void* g, void* l) {
    __builtin_amdgcn_global_load_lds(
        (const __attribute__((address_space(1))) unsigned int*)g,
        (__attribute__((address_space(3))) unsigned int*)l,
        16, 0, 0);
}

// ---------------------------------------------------------------------------
// prep kernel (bid' = bid + base): [0,4096) convert fc -> ws2 image order;
// [4096,5120) init out = bias (needed only for the atomic fallback path).
// ---------------------------------------------------------------------------
__global__ __launch_bounds__(256) void prep_kernel(
    const float* __restrict__ fc, const float* __restrict__ bias,
    unsigned short* __restrict__ ws2, float* __restrict__ out, int base)
{
    const unsigned bid = blockIdx.x + base;
    const unsigned t = threadIdx.x;
    if (bid < 4096) {
        unsigned flat = bid * 256 + t;                // 0 .. 2^20-1
        unsigned bx = flat >> 11, gi = flat & 2047;
        unsigned i = bx >> 1, y = bx & 1;
        unsigned sog = gi >> 6, ll = gi & 63;
        unsigned s = sog >> 3, og = sog & 7;
        unsigned op = og * 16 + (ll & 15);
        unsigned k = s * 32 + ((ll >> 4) * 8);
        unsigned tt = k >> 6, g0 = k & 63;
        const float4* src = (const float4*)(fc +
            ((((size_t)tt * 256 + y * 128 + op) * 256 + i) * 64 + g0));
        float4 a = src[0], b = src[1];
        uint4 v;
        v.x = pkbf16(a.x, a.y); v.y = pkbf16(a.z, a.w);
        v.z = pkbf16(b.x, b.y); v.w = pkbf16(b.z, b.w);
        ((uint4*)ws2)[flat] = v;
    } else {
        int tid = (bid - 4096) * 256 + t;             // 0..262143
        float4 b4 = ((const float4*)bias)[tid & 63];
        ((float4*)out)[tid] = b4;
    }
}

// out = bias + sum_z partial[z]   (flat layout identical to out)
__global__ __launch_bounds__(256) void reduce_kernel(
    const float* __restrict__ pws, const float* __restrict__ bias,
    float* __restrict__ out)
{
    int idx4 = blockIdx.x * 256 + threadIdx.x;        // 0..262143 float4s
    const float4* p4 = (const float4*)pws;
    float4 r = ((const float4*)bias)[idx4 & 63];
    #pragma unroll
    for (int z = 0; z < SPLITK; ++z) {
        float4 v = p4[(size_t)z * 262144 + idx4];
        r.x += v.x; r.y += v.y; r.z += v.z; r.w += v.w;
    }
    ((float4*)out)[idx4] = r;
}

template <bool USE_WS, bool PARTIAL>
__global__ __launch_bounds__(256, 2) void fkan_gemm(
    const float* __restrict__ x, const float* __restrict__ fc,
    const unsigned short* __restrict__ bws, float* __restrict__ out,
    float* __restrict__ pws)
{
    __shared__ uint4 Bimg[2][2048];        // 64 KB: coeff image, double-buffered
    __shared__ float xs[ICHUNK][128];      // 16 KB: x[row][i] transposed

    const int t  = threadIdx.x;
    const int l  = t & 63;
    const int w  = t >> 6;
    const int wr = w >> 1, wc = w & 1;     // 2x2 waves of 64x64
    const int q  = l >> 4;                 // MFMA quad -> k offset 8q
    const int m  = l & 15;                 // MFMA row within 16

    // XCD-aware decode: z (splitK) in low 3 bits -> blocks sharing an
    // i-window co-reside on one XCD and hit L2 for the B stream.
    const int bid = blockIdx.x;
    const int z   = bid & 7;
    const int by  = (bid >> 3) & 1;
    const int bx  = bid >> 4;
    const int rowBase = bx * 128;
    const int iBase   = z * ICHUNK;

    f32x4 acc[4][4];
    #pragma unroll
    for (int a = 0; a < 4; ++a)
        #pragma unroll
        for (int b = 0; b < 4; ++b) acc[a][b] = (f32x4)0.0f;

    auto stageB = [&](int p, int i) {
        if (USE_WS) {
            const unsigned short* base = bws + ((size_t)(i * 2 + by) * 2048) * 8;
            #pragma unroll
            for (int cc = 0; cc < 8; ++cc) {
                int c = cc * 4 + w;
                async_load16(base + (size_t)(c * 64 + l) * 8, (void*)(&Bimg[p][c * 64]));
            }
        } else {
            #pragma unroll
            for (int gg = 0; gg < 8; ++gg) {
                int gi  = gg * 256 + t;
                int sog = gi >> 6, ll = gi & 63;
                int s = sog >> 3, ogb = sog & 7;
                int o = ogb * 16 + (ll & 15);
                int k = s * 32 + (ll >> 4) * 8;
                int tt = k >> 6, g = k & 63;
                const float4* p4 = (const float4*)(fc +
                    ((((size_t)tt * 256 + by * 128 + o) * 256 + i) * 64 + g));
                float4 a = p4[0], b = p4[1];
                uint4 v;
                v.x = pkbf16(a.x, a.y); v.y = pkbf16(a.z, a.w);
                v.z = pkbf16(b.x, b.y); v.w = pkbf16(b.z, b.w);
                Bimg[p][gi] = v;
            }
        }
    };

    // ---- preamble: stage B(iter0) + x tile, one barrier ----
    stageB(0, iBase);
    {
        int r = t >> 1, c0 = (t & 1) * 16;
        const float4* px = (const float4*)(x + (size_t)(rowBase + r) * 256 + iBase + c0);
        float4 v0 = px[0], v1 = px[1], v2 = px[2], v3 = px[3];
        float tmp[16] = { v0.x, v0.y, v0.z, v0.w, v1.x, v1.y, v1.z, v1.w,
                          v2.x, v2.y, v2.z, v2.w, v3.x, v3.y, v3.z, v3.w };
        #pragma unroll
        for (int j = 0; j < 16; ++j) xs[c0 + j][r] = tmp[j];
    }
    __syncthreads();

    #pragma unroll 1
    for (int ii = 0; ii < ICHUNK; ++ii) {
        const int p = ii & 1;

        // 1. async-stage next B into the other buffer (in flight during 2-4)
        if (ii + 1 < ICHUNK) stageB(p ^ 1, iBase + ii + 1);

        // 2. B fragments of current buffer -> regs (16 ds_read_b128)
        short8 bF[4][4];
        #pragma unroll
        for (int s = 0; s < 4; ++s)
            #pragma unroll
            for (int cf = 0; cf < 4; ++cf)
                bF[s][cf] = __builtin_bit_cast(short8,
                    Bimg[p][(s * 8 + wc * 4 + cf) * 64 + l]);

        // 3. synthesize A fragments in registers (HW v_sin/v_cos seeds)
        short8 aF[4][4];   // [rf][s]
        #pragma unroll
        for (int rf = 0; rf < 4; ++rf) {
            float xv = xs[ii][wr * 64 + rf * 16 + m];
            float rev = xv * INV2PI;
            float s1 = __builtin_amdgcn_sinf(rev);
            float c1 = __builtin_amdgcn_cosf(rev);
            const float m1 = c1 + c1;
            float c2, s2, c4, s4, c8, s8, c16, s16, c32, s32;
            dbl2(c1, s1, c2, s2);
            dbl2(c2, s2, c4, s4);
            dbl2(c4, s4, c8, s8);
            dbl2(c8, s8, c16, s16);
            dbl2(c16, s16, c32, s32);
            float c24, s24;
            rot2(c16, s16, c8, s8, c24, s24);
            float cq = (q == 0) ? 1.f : (q == 1) ? c8 : (q == 2) ? c16 : c24;
            float sq = (q == 0) ? 0.f : (q == 1) ? s8 : (q == 2) ? s16 : s24;
            float cq1, sq1, cB, sB, cB1, sB1;
            rot2(cq, sq, c1, s1, cq1, sq1);     // 8q+1
            rot2(cq, sq, c32, s32, cB, sB);     // 8q+32
            rot2(cB, sB, c1, s1, cB1, sB1);     // 8q+33
            aF[rf][0] = chain8(m1, cq, cq1);    // cos, freq 8q+1..8q+8
            aF[rf][1] = chain8(m1, cB, cB1);    // cos, freq 8q+33..
            aF[rf][2] = chain8(m1, sq, sq1);    // sin, freq 8q+1..
            aF[rf][3] = chain8(m1, sB, sB1);    // sin, freq 8q+33..
        }

        // 4. MFMA
        #pragma unroll
        for (int s = 0; s < 4; ++s)
            #pragma unroll
            for (int rf = 0; rf < 4; ++rf)
                #pragma unroll
                for (int cf = 0; cf < 4; ++cf)
                    acc[rf][cf] = __builtin_amdgcn_mfma_f32_16x16x32_bf16(
                        aF[rf][s], bF[s][cf], acc[rf][cf], 0, 0, 0);

        // 5. one barrier: vmcnt drain covered by steps 2-4
        __syncthreads();
    }

    // epilogue: C/D layout col=l&15, row=(l>>4)*4+e
    const int r0 = rowBase + wr * 64 + (l >> 4) * 4;
    const int c0 = by * 128 + wc * 64 + m;
    if (PARTIAL) {
        // store per-z partial tile (plain stores; reduce_kernel sums)
        float* dst = pws + (size_t)z * (4096 * 256);
        #pragma unroll
        for (int rf = 0; rf < 4; ++rf)
            #pragma unroll
            for (int cf = 0; cf < 4; ++cf)
                #pragma unroll
                for (int e = 0; e < 4; ++e)
                    dst[(size_t)(r0 + rf * 16 + e) * 256 + (c0 + cf * 16)] =
                        acc[rf][cf][e];
    } else {
        #pragma unroll
        for (int rf = 0; rf < 4; ++rf)
            #pragma unroll
            for (int cf = 0; cf < 4; ++cf)
                #pragma unroll
                for (int e = 0; e < 4; ++e)
                    atomicAdd(out + (size_t)(r0 + rf * 16 + e) * 256 + (c0 + cf * 16),
                              acc[rf][cf][e]);
    }
}

extern "C" void kernel_launch(void* const* d_in, const int* in_sizes, int n_in,
                              void* d_out, int out_size, void* d_ws, size_t ws_size,
                              hipStream_t stream) {
    const float* x    = (const float*)d_in[0];
    const float* fc   = (const float*)d_in[1];
    const float* bias = (const float*)d_in[2];
    float* out = (float*)d_out;
    unsigned short* bws = (unsigned short*)d_ws;

    const size_t wsCoeff = (size_t)512 * 2048 * 16;          // 16.78 MB coeff image
    const size_t wsFull  = wsCoeff + (size_t)SPLITK * 4096 * 256 * 4;  // +33.55 MB partials
    float* pws = (float*)((char*)d_ws + wsCoeff);

    if (ws_size >= wsFull) {
        // atomic-free path: convert only (no init needed), gemm->partials, reduce
        hipLaunchKernelGGL(prep_kernel, dim3(4096), dim3(256), 0, stream,
                           fc, bias, bws, out, 0);
        hipLaunchKernelGGL((fkan_gemm<true, true>), dim3(512), dim3(256), 0, stream,
                           x, fc, bws, out, pws);
        hipLaunchKernelGGL(reduce_kernel, dim3(1024), dim3(256), 0, stream,
                           pws, bias, out);
    } else if (ws_size >= wsCoeff) {
        hipLaunchKernelGGL(prep_kernel, dim3(5120), dim3(256), 0, stream,
                           fc, bias, bws, out, 0);
        hipLaunchKernelGGL((fkan_gemm<true, false>), dim3(512), dim3(256), 0, stream,
                           x, fc, bws, out, pws);
    } else {
        hipLaunchKernelGGL(prep_kernel, dim3(1024), dim3(256), 0, stream,
                           fc, bias, bws, out, 4096);   // init out only
        hipLaunchKernelGGL((fkan_gemm<false, false>), dim3(512), dim3(256), 0, stream,
                           x, fc, bws, out, pws);
    }
}

// Round 9
// 151.286 us; speedup vs baseline: 1.2260x; 1.1475x over previous
//
#include <hip/hip_runtime.h>
#include <hip/hip_bf16.h>

// ---------------------------------------------------------------------------
// NaiveFourierKANLayer as GEMM:  y = [cos|sin features][4096 x 32768] * W + b
// R9: wave tile 64r x 128c (VALU/MFMA ratio halved vs R8) with 8-wave blocks
// (512x128 tile) to keep 2 waves/SIMD. splitK=16, bf16 partials (ws budget
// unchanged). B dbuf via global_load_lds, one barrier/iter. A-synth math is
// byte-identical to the verified R5-R8 code.
// ---------------------------------------------------------------------------

typedef __attribute__((ext_vector_type(8))) short short8;
typedef __attribute__((ext_vector_type(4))) float f32x4;

#define SPLITK 16
#define ICHUNK (256 / SPLITK)   // 16 i's per block

#define INV2PI 0.15915494309189535f

// ---- bf16 pack helpers ----
__device__ __forceinline__ unsigned short f2bf(float f) {
    unsigned u = __builtin_bit_cast(unsigned, f);
    u += 0x7fffu + ((u >> 16) & 1u);
    return (unsigned short)(u >> 16);
}
#if __has_builtin(__builtin_amdgcn_cvt_pk_bf16_f32)
typedef __attribute__((ext_vector_type(2))) __bf16 bf16x2_t;
__device__ __forceinline__ unsigned pkbf16(float a, float b) {
    bf16x2_t v = __builtin_amdgcn_cvt_pk_bf16_f32(a, b);
    return __builtin_bit_cast(unsigned, v);
}
#else
__device__ __forceinline__ unsigned pkbf16(float a, float b) {
    unsigned ua = __builtin_bit_cast(unsigned, a) + 0x8000u;
    unsigned ub = __builtin_bit_cast(unsigned, b) + 0x8000u;
    return __builtin_amdgcn_perm(ub, ua, 0x07060302u);  // [b.hi16 | a.hi16]
}
#endif

__device__ __forceinline__ void dbl2(float c, float s, float& co, float& so) {
    float t = c + c;
    co = __builtin_fmaf(t, c, -1.f);
    so = t * s;
}
__device__ __forceinline__ void rot2(float c, float s, float cr, float sr,
                                     float& co, float& so) {
    float t = s * sr;
    co = __builtin_fmaf(c, cr, -t);
    float u = s * cr;
    so = __builtin_fmaf(c, sr, u);
}

// 8 consecutive harmonics from seeds f_{-1}, f_0 with multiplier m1=2cos(x)
__device__ __forceinline__ short8 chain8(float m1, float fm1, float f0) {
    unsigned r[4];
    float vp = fm1, v = f0;
    #pragma unroll
    for (int h = 0; h < 4; ++h) {
        float v1 = __builtin_fmaf(m1, v, -vp);
        r[h] = pkbf16(v, v1);
        float v2 = __builtin_fmaf(m1, v1, -v);
        vp = v1; v = v2;
    }
    uint4 u; u.x = r[0]; u.y = r[1]; u.z = r[2]; u.w = r[3];
    return __builtin_bit_cast(short8, u);
}

// async 16B global->LDS
__device__ __forceinline__ void async_load16(const void* g, void* l) {
    __builtin_amdgcn_global_load_lds(
        (const __attribute__((address_space(1))) unsigned int*)g,
        (__attribute__((address_space(3))) unsigned int*)l,
        16, 0, 0);
}

// ---------------------------------------------------------------------------
// prep kernel (bid' = bid + base): [0,4096) convert fc -> ws2 image order
// (one 16B granule per thread); [4096,5120) init out = bias (atomic fallback).
// ---------------------------------------------------------------------------
__global__ __launch_bounds__(256) void prep_kernel(
    const float* __restrict__ fc, const float* __restrict__ bias,
    unsigned short* __restrict__ ws2, float* __restrict__ out, int base)
{
    const unsigned bid = blockIdx.x + base;
    const unsigned t = threadIdx.x;
    if (bid < 4096) {
        unsigned flat = bid * 256 + t;                // 0 .. 2^20-1
        unsigned bx = flat >> 11, gi = flat & 2047;
        unsigned i = bx >> 1, y = bx & 1;
        unsigned sog = gi >> 6, ll = gi & 63;
        unsigned s = sog >> 3, og = sog & 7;
        unsigned op = og * 16 + (ll & 15);
        unsigned k = s * 32 + ((ll >> 4) * 8);
        unsigned tt = k >> 6, g0 = k & 63;
        const float4* src = (const float4*)(fc +
            ((((size_t)tt * 256 + y * 128 + op) * 256 + i) * 64 + g0));
        float4 a = src[0], b = src[1];
        uint4 v;
        v.x = pkbf16(a.x, a.y); v.y = pkbf16(a.z, a.w);
        v.z = pkbf16(b.x, b.y); v.w = pkbf16(b.z, b.w);
        ((uint4*)ws2)[flat] = v;
    } else {
        int tid = (bid - 4096) * 256 + t;             // 0..262143
        float4 b4 = ((const float4*)bias)[tid & 63];
        ((float4*)out)[tid] = b4;
    }
}

// out = bias + sum_z bf16partial[z]
__global__ __launch_bounds__(256) void reduce_kernel(
    const unsigned short* __restrict__ pws, const float* __restrict__ bias,
    float* __restrict__ out)
{
    int idx4 = blockIdx.x * 256 + threadIdx.x;        // 0..262143 float4s
    float4 r = ((const float4*)bias)[idx4 & 63];
    #pragma unroll
    for (int z = 0; z < SPLITK; ++z) {
        ushort4 v = ((const ushort4*)pws)[(size_t)z * 262144 + idx4];
        r.x += __builtin_bit_cast(float, (unsigned)v.x << 16);
        r.y += __builtin_bit_cast(float, (unsigned)v.y << 16);
        r.z += __builtin_bit_cast(float, (unsigned)v.z << 16);
        r.w += __builtin_bit_cast(float, (unsigned)v.w << 16);
    }
    ((float4*)out)[idx4] = r;
}

template <bool USE_WS, bool PARTIAL>
__global__ __launch_bounds__(512, 2) void fkan_gemm(
    const float* __restrict__ x, const float* __restrict__ fc,
    const unsigned short* __restrict__ bws, float* __restrict__ out,
    unsigned short* __restrict__ pws)
{
    __shared__ uint4 Bimg[2][2048];        // 64 KB: coeff image, double-buffered
    __shared__ float xs[ICHUNK][512];      // 32 KB: x[i][row] transposed

    const int t  = threadIdx.x;            // 0..511
    const int l  = t & 63;
    const int w  = t >> 6;                 // row-wave 0..7 (64 rows each)
    const int q  = l >> 4;                 // MFMA quad -> k offset 8q
    const int m  = l & 15;                 // MFMA row within 16

    // decode: z (splitK) in low 4 bits -> XCD = bid&7 keyed by i-window
    const int bid = blockIdx.x;
    const int z   = bid & 15;
    const int by  = (bid >> 4) & 1;
    const int bx  = bid >> 5;
    const int rowBase = bx * 512;
    const int iBase   = z * ICHUNK;

    f32x4 acc[4][8];
    #pragma unroll
    for (int a = 0; a < 4; ++a)
        #pragma unroll
        for (int b = 0; b < 8; ++b) acc[a][b] = (f32x4)0.0f;

    auto stageB = [&](int p, int i) {
        if (USE_WS) {
            const uint4* base = (const uint4*)bws + (size_t)(i * 2 + by) * 2048;
            #pragma unroll
            for (int cc = 0; cc < 4; ++cc) {
                int c = cc * 8 + w;                 // wave-uniform chunk id
                async_load16(base + (size_t)c * 64 + l, (void*)(&Bimg[p][c * 64]));
            }
        } else {
            #pragma unroll
            for (int gg = 0; gg < 4; ++gg) {
                int gi  = gg * 512 + t;
                int sog = gi >> 6, ll = gi & 63;
                int s = sog >> 3, ogb = sog & 7;
                int o = ogb * 16 + (ll & 15);
                int k = s * 32 + (ll >> 4) * 8;
                int tt = k >> 6, g = k & 63;
                const float4* p4 = (const float4*)(fc +
                    ((((size_t)tt * 256 + by * 128 + o) * 256 + i) * 64 + g));
                float4 a = p4[0], b = p4[1];
                uint4 v;
                v.x = pkbf16(a.x, a.y); v.y = pkbf16(a.z, a.w);
                v.z = pkbf16(b.x, b.y); v.w = pkbf16(b.z, b.w);
                Bimg[p][gi] = v;
            }
        }
    };

    // ---- preamble: stage B(iter0) + x tile, one barrier ----
    stageB(0, iBase);
    {
        const float4* px = (const float4*)(x + (size_t)(rowBase + t) * 256 + iBase);
        #pragma unroll
        for (int j4 = 0; j4 < 4; ++j4) {
            float4 v = px[j4];
            xs[j4 * 4 + 0][t] = v.x;
            xs[j4 * 4 + 1][t] = v.y;
            xs[j4 * 4 + 2][t] = v.z;
            xs[j4 * 4 + 3][t] = v.w;
        }
    }
    __syncthreads();

    #pragma unroll 1
    for (int ii = 0; ii < ICHUNK; ++ii) {
        const int p = ii & 1;

        // 1. async-stage next B into the other buffer (in flight during 2-3)
        if (ii + 1 < ICHUNK) stageB(p ^ 1, iBase + ii + 1);

        // 2. synthesize A fragments in registers (verified R5 math, verbatim)
        short8 aF[4][4];   // [rf][s]
        #pragma unroll
        for (int rf = 0; rf < 4; ++rf) {
            float xv = xs[ii][w * 64 + rf * 16 + m];
            float rev = xv * INV2PI;
            float s1 = __builtin_amdgcn_sinf(rev);
            float c1 = __builtin_amdgcn_cosf(rev);
            const float m1 = c1 + c1;
            float c2, s2, c4, s4, c8, s8, c16, s16, c32, s32;
            dbl2(c1, s1, c2, s2);
            dbl2(c2, s2, c4, s4);
            dbl2(c4, s4, c8, s8);
            dbl2(c8, s8, c16, s16);
            dbl2(c16, s16, c32, s32);
            float c24, s24;
            rot2(c16, s16, c8, s8, c24, s24);
            float cq = (q == 0) ? 1.f : (q == 1) ? c8 : (q == 2) ? c16 : c24;
            float sq = (q == 0) ? 0.f : (q == 1) ? s8 : (q == 2) ? s16 : s24;
            float cq1, sq1, cB, sB, cB1, sB1;
            rot2(cq, sq, c1, s1, cq1, sq1);     // 8q+1
            rot2(cq, sq, c32, s32, cB, sB);     // 8q+32
            rot2(cB, sB, c1, s1, cB1, sB1);     // 8q+33
            aF[rf][0] = chain8(m1, cq, cq1);    // cos, freq 8q+1..8q+8
            aF[rf][1] = chain8(m1, cB, cB1);    // cos, freq 8q+33..
            aF[rf][2] = chain8(m1, sq, sq1);    // sin, freq 8q+1..
            aF[rf][3] = chain8(m1, sB, sB1);    // sin, freq 8q+33..
        }

        // 3. MFMA: per s, read 8 B-fragments (full 128 cols) then 32 MFMAs
        #pragma unroll
        for (int s = 0; s < 4; ++s) {
            short8 bF[8];
            #pragma unroll
            for (int cf = 0; cf < 8; ++cf)
                bF[cf] = __builtin_bit_cast(short8, Bimg[p][(s * 8 + cf) * 64 + l]);
            #pragma unroll
            for (int rf = 0; rf < 4; ++rf)
                #pragma unroll
                for (int cf = 0; cf < 8; ++cf)
                    acc[rf][cf] = __builtin_amdgcn_mfma_f32_16x16x32_bf16(
                        aF[rf][s], bF[cf], acc[rf][cf], 0, 0, 0);
        }

        // 4. one barrier: vmcnt drain covered by steps 2-3
        __syncthreads();
    }

    // epilogue: C/D layout col=l&15, row=(l>>4)*4+e
    const int r0 = rowBase + w * 64 + (l >> 4) * 4;
    const int c0 = by * 128 + m;
    if (PARTIAL) {
        unsigned short* dst = pws + (size_t)z * (4096u * 256u);
        #pragma unroll
        for (int rf = 0; rf < 4; ++rf)
            #pragma unroll
            for (int cf = 0; cf < 8; ++cf)
                #pragma unroll
                for (int e = 0; e < 4; ++e)
                    dst[(size_t)(r0 + rf * 16 + e) * 256 + (c0 + cf * 16)] =
                        f2bf(acc[rf][cf][e]);
    } else {
        #pragma unroll
        for (int rf = 0; rf < 4; ++rf)
            #pragma unroll
            for (int cf = 0; cf < 8; ++cf)
                #pragma unroll
                for (int e = 0; e < 4; ++e)
                    atomicAdd(out + (size_t)(r0 + rf * 16 + e) * 256 + (c0 + cf * 16),
                              acc[rf][cf][e]);
    }
}

extern "C" void kernel_launch(void* const* d_in, const int* in_sizes, int n_in,
                              void* d_out, int out_size, void* d_ws, size_t ws_size,
                              hipStream_t stream) {
    const float* x    = (const float*)d_in[0];
    const float* fc   = (const float*)d_in[1];
    const float* bias = (const float*)d_in[2];
    float* out = (float*)d_out;
    unsigned short* bws = (unsigned short*)d_ws;

    const size_t wsCoeff = (size_t)512 * 2048 * 16;                     // 16.78 MB
    const size_t wsFull  = wsCoeff + (size_t)SPLITK * 4096 * 256 * 2;   // +33.55 MB bf16 partials
    unsigned short* pws = (unsigned short*)((char*)d_ws + wsCoeff);

    if (ws_size >= wsFull) {
        hipLaunchKernelGGL(prep_kernel, dim3(4096), dim3(256), 0, stream,
                           fc, bias, bws, out, 0);
        hipLaunchKernelGGL((fkan_gemm<true, true>), dim3(256), dim3(512), 0, stream,
                           x, fc, bws, out, pws);
        hipLaunchKernelGGL(reduce_kernel, dim3(1024), dim3(256), 0, stream,
                           pws, bias, out);
    } else if (ws_size >= wsCoeff) {
        hipLaunchKernelGGL(prep_kernel, dim3(5120), dim3(256), 0, stream,
                           fc, bias, bws, out, 0);
        hipLaunchKernelGGL((fkan_gemm<true, false>), dim3(256), dim3(512), 0, stream,
                           x, fc, bws, out, pws);
    } else {
        hipLaunchKernelGGL(prep_kernel, dim3(1024), dim3(256), 0, stream,
                           fc, bias, bws, out, 4096);   // init out only
        hipLaunchKernelGGL((fkan_gemm<false, false>), dim3(256), dim3(512), 0, stream,
                           x, fc, bws, out, pws);
    }
}